// Round 2
// baseline (252.874 us; speedup 1.0000x reference)
//
#include <hip/hip_runtime.h>
#include <cstdint>

#define TOK 2048
#define EMB 768
#define WIN 64

typedef __attribute__((ext_vector_type(8))) __bf16 bf16x8;
typedef __attribute__((ext_vector_type(4))) float f32x4;

static __device__ __forceinline__ unsigned short f2bf(float f) {
  uint32_t x = __float_as_uint(f);
  uint32_t r = (x + 0x7fffu + ((x >> 16) & 1u)) >> 16;  // RNE
  return (unsigned short)r;
}
static __device__ __forceinline__ float bf2f(unsigned short u) {
  return __uint_as_float(((uint32_t)u) << 16);
}

static __device__ __forceinline__ void gload_lds16(const void* g, void* l) {
  __builtin_amdgcn_global_load_lds(
      (const __attribute__((address_space(1))) uint32_t*)g,
      (__attribute__((address_space(3))) uint32_t*)l, 16, 0, 0);
}

// ---------------- prep: inputs -> bf16 hi/lo ----------------
__global__ __launch_bounds__(256) void cvt_inputs(
    const float* __restrict__ a0, const float* __restrict__ a1,
    const float* __restrict__ a2, unsigned short* __restrict__ hi,
    unsigned short* __restrict__ lo) {
  const int64_t NE4 = (int64_t)TOK * EMB / 4;  // float4 per input
  int64_t i = (int64_t)blockIdx.x * blockDim.x + threadIdx.x;
  if (i >= 3 * NE4) return;
  int which = (int)(i / NE4);
  int64_t loc = i - (int64_t)which * NE4;
  const float4* src = (const float4*)(which == 0 ? a0 : which == 1 ? a1 : a2);
  float4 x = src[loc];
  float fx[4] = {x.x, x.y, x.z, x.w};
  ushort4 h, l;
  unsigned short hh[4], ll[4];
#pragma unroll
  for (int j = 0; j < 4; ++j) {
    hh[j] = f2bf(fx[j]);
    ll[j] = f2bf(fx[j] - bf2f(hh[j]));
  }
  h.x = hh[0]; h.y = hh[1]; h.z = hh[2]; h.w = hh[3];
  l.x = ll[0]; l.y = ll[1]; l.z = ll[2]; l.w = ll[3];
  ((ushort4*)hi)[i] = h;
  ((ushort4*)lo)[i] = l;
}

// ---------------- prep: weights -> transposed bf16 hi/lo ----------------
__global__ void cvt_wT(const float* __restrict__ w0, const float* __restrict__ w1,
                       const float* __restrict__ w2,
                       unsigned short* __restrict__ hiT,
                       unsigned short* __restrict__ loT) {
  __shared__ float t[32][33];
  const int z = blockIdx.z;
  const float* w = (z == 0) ? w0 : (z == 1) ? w1 : w2;
  const int d0 = blockIdx.x * 32, e0 = blockIdx.y * 32;
  const int tx = threadIdx.x, ty = threadIdx.y;  // (32,8)
#pragma unroll
  for (int r = 0; r < 4; ++r)
    t[ty + r * 8][tx] = w[(size_t)(e0 + ty + r * 8) * EMB + d0 + tx];
  __syncthreads();
#pragma unroll
  for (int r = 0; r < 4; ++r) {
    const int dl = ty + r * 8, el = tx;
    const float f = t[el][dl];  // = W[e0+el][d0+dl]
    const size_t o = (size_t)z * EMB * EMB + (size_t)(d0 + dl) * EMB + e0 + el;
    unsigned short h = f2bf(f);
    hiT[o] = h;
    loT[o] = f2bf(f - bf2f(h));
  }
}

// ---------------- projections: split-bf16 MFMA GEMM ----------------
__global__ __launch_bounds__(256) void proj_gemm(
    const unsigned short* __restrict__ Ahi, const unsigned short* __restrict__ Alo,
    const unsigned short* __restrict__ WThi, const unsigned short* __restrict__ WTlo,
    float* __restrict__ outkvq) {
  const int z = blockIdx.z;
  const int bn0 = blockIdx.x * 128;  // output col (D)
  const int bm0 = blockIdx.y * 128;  // output row (token)
  const int tid = threadIdx.x, lane = tid & 63, w = tid >> 6;
  const int wr = w >> 1, wc = w & 1;

  __shared__ unsigned short lA[128 * 32];
  __shared__ unsigned short lB[128 * 32];

  const unsigned short* Ah = Ahi + (size_t)z * TOK * EMB;
  const unsigned short* Al = Alo + (size_t)z * TOK * EMB;
  const unsigned short* Bh = WThi + (size_t)z * EMB * EMB;
  const unsigned short* Bl = WTlo + (size_t)z * EMB * EMB;

  f32x4 acc[4][4] = {};

  const int sr = lane >> 2;          // row within 16-row chunk
  const int sk = (lane & 3) * 8;     // k element offset (16B)

  for (int ph = 0; ph < 3; ++ph) {
    const unsigned short* Asrc = (ph == 1) ? Al : Ah;
    const unsigned short* Bsrc = (ph == 2) ? Bl : Bh;
    for (int kk = 0; kk < EMB; kk += 32) {
      __syncthreads();
#pragma unroll
      for (int c = 0; c < 2; ++c) {
        const int chunk = w * 2 + c;            // 0..7, 16 rows each
        const int row = chunk * 16 + sr;
        gload_lds16(Asrc + (size_t)(bm0 + row) * EMB + kk + sk,
                    (char*)lA + chunk * 1024);
        gload_lds16(Bsrc + (size_t)(bn0 + row) * EMB + kk + sk,
                    (char*)lB + chunk * 1024);
      }
      __syncthreads();

      bf16x8 af[4], bfr[4];
#pragma unroll
      for (int m = 0; m < 4; ++m)
        af[m] = *(const bf16x8*)&lA[(wr * 64 + m * 16 + (lane & 15)) * 32 +
                                    (lane >> 4) * 8];
#pragma unroll
      for (int n = 0; n < 4; ++n)
        bfr[n] = *(const bf16x8*)&lB[(wc * 64 + n * 16 + (lane & 15)) * 32 +
                                     (lane >> 4) * 8];
#pragma unroll
      for (int m = 0; m < 4; ++m)
#pragma unroll
        for (int n = 0; n < 4; ++n)
          acc[m][n] = __builtin_amdgcn_mfma_f32_16x16x32_bf16(af[m], bfr[n],
                                                              acc[m][n], 0, 0, 0);
    }
  }

  float* C = outkvq + (size_t)z * TOK * EMB;
#pragma unroll
  for (int m = 0; m < 4; ++m) {
    const int row = bm0 + wr * 64 + m * 16 + (lane >> 4) * 4;
#pragma unroll
    for (int n = 0; n < 4; ++n) {
      const int col = bn0 + wc * 64 + n * 16 + (lane & 15);
#pragma unroll
      for (int r = 0; r < 4; ++r)
        C[(size_t)(row + r) * EMB + col] = acc[m][n][r];
    }
  }
}

// ---------------- sliding-window attention v2 (fp32, wave-per-query) ------
// 8 waves/block, wave w owns query t0+w. Lane l owns keys {l, l+64, l+128}
// and accumulates full dots IN-LANE (no per-key reduce). One shuffle reduce
// per query for max/sum. PV: lanes own d (3x float4). XCD swizzle for L2.
__global__ __launch_bounds__(512) void attn(const float* __restrict__ kf,
                                            const float* __restrict__ vf,
                                            const float* __restrict__ qf,
                                            float* __restrict__ out) {
  // XCD-aware swizzle: 256 blocks, 8 XCDs -> contiguous 32-block chunks
  const int bid = ((int)blockIdx.x % 8) * 32 + (int)blockIdx.x / 8;
  const int t0 = bid * 8;
  const int tid = threadIdx.x, lane = tid & 63, w = tid >> 6;
  __shared__ float q_s[8][EMB];
  __shared__ float sc[8][192];
  __shared__ float rcpb[8];

  const int start0 = max(0, t0 - WIN);
  const int U = min(TOK, t0 + 7 + WIN + 1) - start0;  // <= 136

  // stage q (float4, coalesced)
  for (int i = tid; i < 8 * (EMB / 4); i += 512) {
    const int row = i / (EMB / 4), c4 = i - row * (EMB / 4);
    ((float4*)q_s[row])[c4] = ((const float4*)(qf + (size_t)(t0 + row) * EMB))[c4];
  }
  __syncthreads();

  const int t = t0 + w;
  const int sL = max(0, t - WIN), eL = min(TOK, t + WIN + 1);

  // ---- scores: in-lane dot over d ----
  const int jl0 = lane, jl1 = lane + 64, jl2 = lane + 128;
  const int j0 = min(start0 + jl0, TOK - 1);
  const int j1 = min(start0 + jl1, TOK - 1);
  const int j2 = min(start0 + jl2, TOK - 1);
  const float4* __restrict__ k0 = (const float4*)(kf + (size_t)j0 * EMB);
  const float4* __restrict__ k1 = (const float4*)(kf + (size_t)j1 * EMB);
  const float4* __restrict__ k2 = (const float4*)(kf + (size_t)j2 * EMB);
  const float4* __restrict__ qp = (const float4*)q_s[w];

  float s0 = 0.f, s1 = 0.f, s2 = 0.f;
#pragma unroll 4
  for (int d4 = 0; d4 < EMB / 4; ++d4) {
    const float4 qv = qp[d4];
    const float4 a = k0[d4];
    const float4 b = k1[d4];
    const float4 c = k2[d4];
    s0 = fmaf(qv.x, a.x, fmaf(qv.y, a.y, fmaf(qv.z, a.z, fmaf(qv.w, a.w, s0))));
    s1 = fmaf(qv.x, b.x, fmaf(qv.y, b.y, fmaf(qv.z, b.z, fmaf(qv.w, b.w, s1))));
    s2 = fmaf(qv.x, c.x, fmaf(qv.y, c.y, fmaf(qv.z, c.z, fmaf(qv.w, c.w, s2))));
  }

  const float SC = 0.03608439182435161f;  // 768^-0.5
  const bool v0 = (jl0 < U) && (start0 + jl0 >= sL) && (start0 + jl0 < eL);
  const bool v1 = (jl1 < U) && (start0 + jl1 >= sL) && (start0 + jl1 < eL);
  const bool v2 = (jl2 < U) && (start0 + jl2 >= sL) && (start0 + jl2 < eL);
  float x0 = v0 ? s0 * SC : -1e30f;
  float x1 = v1 ? s1 * SC : -1e30f;
  float x2 = v2 ? s2 * SC : -1e30f;

  float m = fmaxf(x0, fmaxf(x1, x2));
#pragma unroll
  for (int off = 32; off > 0; off >>= 1) m = fmaxf(m, __shfl_xor(m, off));
  const float e0 = __expf(x0 - m), e1 = __expf(x1 - m), e2 = __expf(x2 - m);
  float sum = e0 + e1 + e2;
#pragma unroll
  for (int off = 32; off > 0; off >>= 1) sum += __shfl_xor(sum, off);

  sc[w][jl0] = e0;
  sc[w][jl1] = e1;
  sc[w][jl2] = e2;
  if (lane == 0) rcpb[w] = 1.0f / (sum * (float)(eL - sL));

  // ---- PV: lanes own d; loop exactly this query's window ----
  // (wave-private: sc[w]/rcpb[w] written by this wave; compiler orders via lgkmcnt)
  float4 a0 = {0, 0, 0, 0}, a1 = {0, 0, 0, 0}, a2 = {0, 0, 0, 0};
  const int lo = sL - start0, hi = eL - start0;
#pragma unroll 2
  for (int jl = lo; jl < hi; ++jl) {
    const float p = sc[w][jl];
    const float4* __restrict__ vp = (const float4*)(vf + (size_t)(start0 + jl) * EMB);
    const float4 b0 = vp[lane], b1 = vp[lane + 64], b2 = vp[lane + 128];
    a0.x = fmaf(p, b0.x, a0.x); a0.y = fmaf(p, b0.y, a0.y);
    a0.z = fmaf(p, b0.z, a0.z); a0.w = fmaf(p, b0.w, a0.w);
    a1.x = fmaf(p, b1.x, a1.x); a1.y = fmaf(p, b1.y, a1.y);
    a1.z = fmaf(p, b1.z, a1.z); a1.w = fmaf(p, b1.w, a1.w);
    a2.x = fmaf(p, b2.x, a2.x); a2.y = fmaf(p, b2.y, a2.y);
    a2.z = fmaf(p, b2.z, a2.z); a2.w = fmaf(p, b2.w, a2.w);
  }
  const float r = rcpb[w];
  float4* __restrict__ op = (float4*)(out + (size_t)t * EMB);
  float4 o0 = {a0.x * r, a0.y * r, a0.z * r, a0.w * r};
  float4 o1 = {a1.x * r, a1.y * r, a1.z * r, a1.w * r};
  float4 o2 = {a2.x * r, a2.y * r, a2.z * r, a2.w * r};
  op[lane] = o0;
  op[lane + 64] = o1;
  op[lane + 128] = o2;
}

extern "C" void kernel_launch(void* const* d_in, const int* in_sizes, int n_in,
                              void* d_out, int out_size, void* d_ws, size_t ws_size,
                              hipStream_t stream) {
  const float* key = (const float*)d_in[0];
  const float* value = (const float*)d_in[1];
  const float* query = (const float*)d_in[2];
  const float* Wk = (const float*)d_in[3];
  const float* Wv = (const float*)d_in[4];
  const float* Wq = (const float*)d_in[5];

  char* ws = (char*)d_ws;
  const size_t NA = (size_t)3 * TOK * EMB;
  const size_t NW = (size_t)3 * EMB * EMB;
  unsigned short* Ahi = (unsigned short*)ws;
  unsigned short* Alo = Ahi + NA;
  unsigned short* WThi = Alo + NA;
  unsigned short* WTlo = WThi + NW;
  float* kvq = (float*)(WTlo + NW);
  float* kf = kvq;
  float* vf = kvq + (size_t)TOK * EMB;
  float* qf = kvq + (size_t)2 * TOK * EMB;
  float* out = (float*)d_out;

  cvt_inputs<<<(3 * TOK * EMB / 4 + 255) / 256, 256, 0, stream>>>(
      key, value, query, Ahi, Alo);
  cvt_wT<<<dim3(EMB / 32, EMB / 32, 3), dim3(32, 8), 0, stream>>>(
      Wk, Wv, Wq, WThi, WTlo);
  proj_gemm<<<dim3(EMB / 128, TOK / 128, 3), 256, 0, stream>>>(
      Ahi, Alo, WThi, WTlo, kvq);
  attn<<<TOK / 8, 512, 0, stream>>>(kf, vf, qf, out);
}

// Round 3
// 115.916 us; speedup vs baseline: 2.1815x; 2.1815x over previous
//
#include <hip/hip_runtime.h>
#include <cstdint>

#define TOK 2048
#define EMB 768
#define WIN 64

typedef __attribute__((ext_vector_type(8))) __bf16 bf16x8;
typedef __attribute__((ext_vector_type(4))) float f32x4;

static __device__ __forceinline__ unsigned short f2bf(float f) {
  uint32_t x = __float_as_uint(f);
  uint32_t r = (x + 0x7fffu + ((x >> 16) & 1u)) >> 16;  // RNE
  return (unsigned short)r;
}
static __device__ __forceinline__ float bf2f(unsigned short u) {
  return __uint_as_float(((uint32_t)u) << 16);
}

static __device__ __forceinline__ void gload_lds16(const void* g, void* l) {
  __builtin_amdgcn_global_load_lds(
      (const __attribute__((address_space(1))) uint32_t*)g,
      (__attribute__((address_space(3))) uint32_t*)l, 16, 0, 0);
}

// ---------------- prep: inputs -> bf16 (hi only; A is plain bf16 now) ------
__global__ __launch_bounds__(256) void cvt_inputs(
    const float* __restrict__ a0, const float* __restrict__ a1,
    const float* __restrict__ a2, unsigned short* __restrict__ hi) {
  const int64_t NE4 = (int64_t)TOK * EMB / 4;
  int64_t i = (int64_t)blockIdx.x * blockDim.x + threadIdx.x;
  if (i >= 3 * NE4) return;
  int which = (int)(i / NE4);
  int64_t loc = i - (int64_t)which * NE4;
  const float4* src = (const float4*)(which == 0 ? a0 : which == 1 ? a1 : a2);
  float4 x = src[loc];
  ushort4 h;
  h.x = f2bf(x.x); h.y = f2bf(x.y); h.z = f2bf(x.z); h.w = f2bf(x.w);
  ((ushort4*)hi)[i] = h;
}

// ---------------- prep: weights -> transposed bf16 hi/lo ----------------
__global__ void cvt_wT(const float* __restrict__ w0, const float* __restrict__ w1,
                       const float* __restrict__ w2,
                       unsigned short* __restrict__ hiT,
                       unsigned short* __restrict__ loT) {
  __shared__ float t[32][33];
  const int z = blockIdx.z;
  const float* w = (z == 0) ? w0 : (z == 1) ? w1 : w2;
  const int d0 = blockIdx.x * 32, e0 = blockIdx.y * 32;
  const int tx = threadIdx.x, ty = threadIdx.y;  // (32,8)
#pragma unroll
  for (int r = 0; r < 4; ++r)
    t[ty + r * 8][tx] = w[(size_t)(e0 + ty + r * 8) * EMB + d0 + tx];
  __syncthreads();
#pragma unroll
  for (int r = 0; r < 4; ++r) {
    const int dl = ty + r * 8, el = tx;
    const float f = t[el][dl];  // = W[e0+el][d0+dl]
    const size_t o = (size_t)z * EMB * EMB + (size_t)(d0 + dl) * EMB + e0 + el;
    unsigned short h = f2bf(f);
    hiT[o] = h;
    loT[o] = f2bf(f - bf2f(h));
  }
}

// ---------------- projections: 2-term split-bf16 MFMA GEMM ----------------
// C = Abf@Bhi + Abf@Blo (= Abf@B exactly up to fp32 accum).
// BM=64, BN=128 -> grid (6,32,3) = 576 blocks for occupancy.
__global__ __launch_bounds__(256) void proj_gemm(
    const unsigned short* __restrict__ Ab, const unsigned short* __restrict__ WThi,
    const unsigned short* __restrict__ WTlo, float* __restrict__ outkvq) {
  const int z = blockIdx.z;
  const int bn0 = blockIdx.x * 128;  // output col (D)
  const int bm0 = blockIdx.y * 64;   // output row (token)
  const int tid = threadIdx.x, lane = tid & 63, w = tid >> 6;
  const int wr = w >> 1, wc = w & 1;

  __shared__ unsigned short lA[64 * 32];    // 4KB
  __shared__ unsigned short lB[128 * 32];   // 8KB

  const unsigned short* Ah = Ab + (size_t)z * TOK * EMB;
  const unsigned short* Bh = WThi + (size_t)z * EMB * EMB;
  const unsigned short* Bl = WTlo + (size_t)z * EMB * EMB;

  f32x4 acc[2][4] = {};

  const int sr = lane >> 2;       // row within 16-row chunk
  const int sk = (lane & 3) * 8;  // k element offset (16B)

  for (int ph = 0; ph < 2; ++ph) {
    const unsigned short* Bsrc = (ph == 1) ? Bl : Bh;
    for (int kk = 0; kk < EMB; kk += 32) {
      __syncthreads();
#pragma unroll
      for (int c = 0; c < 3; ++c) {
        const int chunk = w + c * 4;  // 0..11: 0-3 A(64 rows), 4-11 B(128 rows)
        if (chunk < 4) {
          gload_lds16(Ah + (size_t)(bm0 + chunk * 16 + sr) * EMB + kk + sk,
                      (char*)lA + chunk * 1024);
        } else {
          const int bc = chunk - 4;
          gload_lds16(Bsrc + (size_t)(bn0 + bc * 16 + sr) * EMB + kk + sk,
                      (char*)lB + bc * 1024);
        }
      }
      __syncthreads();

      bf16x8 af[2], bfr[4];
#pragma unroll
      for (int m = 0; m < 2; ++m)
        af[m] = *(const bf16x8*)&lA[(wr * 32 + m * 16 + (lane & 15)) * 32 +
                                    (lane >> 4) * 8];
#pragma unroll
      for (int n = 0; n < 4; ++n)
        bfr[n] = *(const bf16x8*)&lB[(wc * 64 + n * 16 + (lane & 15)) * 32 +
                                     (lane >> 4) * 8];
#pragma unroll
      for (int m = 0; m < 2; ++m)
#pragma unroll
        for (int n = 0; n < 4; ++n)
          acc[m][n] = __builtin_amdgcn_mfma_f32_16x16x32_bf16(af[m], bfr[n],
                                                              acc[m][n], 0, 0, 0);
    }
  }

  float* C = outkvq + (size_t)z * TOK * EMB;
#pragma unroll
  for (int m = 0; m < 2; ++m) {
    const int row = bm0 + wr * 32 + m * 16 + (lane >> 4) * 4;
#pragma unroll
    for (int n = 0; n < 4; ++n) {
      const int col = bn0 + wc * 64 + n * 16 + (lane & 15);
#pragma unroll
      for (int r = 0; r < 4; ++r)
        C[(size_t)(row + r) * EMB + col] = acc[m][n][r];
    }
  }
}

// ---------------- sliding-window attention v3 ----------------
// NQ=4 queries/block, 512 blocks (2/CU), 8 waves (16 waves/CU = 50% cap).
// All global loads: wave-uniform row, lanes span d -> coalesced.
__global__ __launch_bounds__(512, 4) void attn(const float* __restrict__ kf,
                                               const float* __restrict__ vf,
                                               const float* __restrict__ qf,
                                               float* __restrict__ out) {
  // XCD swizzle: 512 blocks -> 8 chunks of 64
  const int bid = ((int)blockIdx.x % 8) * 64 + (int)blockIdx.x / 8;
  const int t0 = bid * 4;
  const int tid = threadIdx.x, lane = tid & 63, w = tid >> 6;  // w: 0..7
  __shared__ float q_s[4][EMB];   // 12KB
  __shared__ float sc[4][136];    // exp'd scores (valid slots only)
  __shared__ float rcpb[4];

  const int start0 = max(0, t0 - WIN);
  const int U = min(TOK, t0 + 3 + WIN + 1) - start0;  // <= 132

  // stage q (coalesced float4)
  for (int i = tid; i < 4 * (EMB / 4); i += 512) {
    const int row = i / (EMB / 4), c4 = i - row * (EMB / 4);
    ((float4*)q_s[row])[c4] = ((const float4*)(qf + (size_t)(t0 + row) * EMB))[c4];
  }
  __syncthreads();

  // q fragments in registers: 4 queries x 3 float4 = 48 VGPR
  float4 qr[4][3];
#pragma unroll
  for (int qi = 0; qi < 4; ++qi)
#pragma unroll
    for (int i = 0; i < 3; ++i) qr[qi][i] = ((const float4*)q_s[qi])[lane + 64 * i];

  const float SC = 0.03608439182435161f;  // 768^-0.5

  // ---- scores: wave-strided keys, coalesced k loads ----
  for (int jl = w; jl < U; jl += 8) {
    const int j = start0 + jl;
    const float4* __restrict__ kp = (const float4*)(kf + (size_t)j * EMB);
    const float4 k0 = kp[lane], k1 = kp[lane + 64], k2 = kp[lane + 128];
    float dd[4];
#pragma unroll
    for (int qi = 0; qi < 4; ++qi) {
      float s = 0.f;
      s = fmaf(qr[qi][0].x, k0.x, s); s = fmaf(qr[qi][0].y, k0.y, s);
      s = fmaf(qr[qi][0].z, k0.z, s); s = fmaf(qr[qi][0].w, k0.w, s);
      s = fmaf(qr[qi][1].x, k1.x, s); s = fmaf(qr[qi][1].y, k1.y, s);
      s = fmaf(qr[qi][1].z, k1.z, s); s = fmaf(qr[qi][1].w, k1.w, s);
      s = fmaf(qr[qi][2].x, k2.x, s); s = fmaf(qr[qi][2].y, k2.y, s);
      s = fmaf(qr[qi][2].z, k2.z, s); s = fmaf(qr[qi][2].w, k2.w, s);
      dd[qi] = s;
    }
#pragma unroll
    for (int qi = 0; qi < 4; ++qi) {
      float v = dd[qi];
#pragma unroll
      for (int off = 32; off > 0; off >>= 1) v += __shfl_xor(v, off);
      dd[qi] = v;
    }
    if (lane < 4) {
      const int t = t0 + lane;
      if (j >= max(0, t - WIN) && j < min(TOK, t + WIN + 1)) {
        float val = dd[0];
        val = (lane == 1) ? dd[1] : val;
        val = (lane == 2) ? dd[2] : val;
        val = (lane == 3) ? dd[3] : val;
        sc[lane][jl] = val * SC;
      }
    }
  }
  __syncthreads();

  // ---- softmax: wave w<4 handles query w over its exact range ----
  if (w < 4) {
    const int t = t0 + w;
    const int sL = max(0, t - WIN), eL = min(TOK, t + WIN + 1);
    const int lo = sL - start0, len = eL - sL;  // len <= 129
    const float x0 = (lane < len) ? sc[w][lo + lane] : -1e30f;
    const float x1 = (lane + 64 < len) ? sc[w][lo + 64 + lane] : -1e30f;
    const float x2 = (lane + 128 < len) ? sc[w][lo + 128 + lane] : -1e30f;
    float m = fmaxf(x0, fmaxf(x1, x2));
#pragma unroll
    for (int off = 32; off > 0; off >>= 1) m = fmaxf(m, __shfl_xor(m, off));
    const float e0 = __expf(x0 - m), e1 = __expf(x1 - m), e2 = __expf(x2 - m);
    float sum = (lane < len ? e0 : 0.f) + (lane + 64 < len ? e1 : 0.f) +
                (lane + 128 < len ? e2 : 0.f);
#pragma unroll
    for (int off = 32; off > 0; off >>= 1) sum += __shfl_xor(sum, off);
    if (lane < len) sc[w][lo + lane] = e0;
    if (lane + 64 < len) sc[w][lo + 64 + lane] = e1;
    if (lane + 128 < len) sc[w][lo + 128 + lane] = e2;
    if (lane == 0) rcpb[w] = 1.0f / (sum * (float)len);
  }
  __syncthreads();

  // ---- PV: wave = (query, d-half); float2 lanes, coalesced ----
  const int qi = w & 3, h = w >> 2;
  const int t = t0 + qi;
  const int sL = max(0, t - WIN), eL = min(TOK, t + WIN + 1);
  const int lo = sL - start0, hi2 = eL - start0;
  float2 a0 = {0, 0}, a1 = {0, 0}, a2 = {0, 0};
  for (int jl = lo; jl < hi2; ++jl) {
    const float p = sc[qi][jl];
    const float2* __restrict__ vp =
        (const float2*)(vf + (size_t)(start0 + jl) * EMB + h * 384);
    const float2 b0 = vp[lane], b1 = vp[lane + 64], b2 = vp[lane + 128];
    a0.x = fmaf(p, b0.x, a0.x); a0.y = fmaf(p, b0.y, a0.y);
    a1.x = fmaf(p, b1.x, a1.x); a1.y = fmaf(p, b1.y, a1.y);
    a2.x = fmaf(p, b2.x, a2.x); a2.y = fmaf(p, b2.y, a2.y);
  }
  const float r = rcpb[qi];
  float2* __restrict__ op = (float2*)(out + (size_t)t * EMB + h * 384);
  float2 o0 = {a0.x * r, a0.y * r};
  float2 o1 = {a1.x * r, a1.y * r};
  float2 o2 = {a2.x * r, a2.y * r};
  op[lane] = o0;
  op[lane + 64] = o1;
  op[lane + 128] = o2;
}

extern "C" void kernel_launch(void* const* d_in, const int* in_sizes, int n_in,
                              void* d_out, int out_size, void* d_ws, size_t ws_size,
                              hipStream_t stream) {
  const float* key = (const float*)d_in[0];
  const float* value = (const float*)d_in[1];
  const float* query = (const float*)d_in[2];
  const float* Wk = (const float*)d_in[3];
  const float* Wv = (const float*)d_in[4];
  const float* Wq = (const float*)d_in[5];

  char* ws = (char*)d_ws;
  const size_t NA = (size_t)3 * TOK * EMB;
  const size_t NW = (size_t)3 * EMB * EMB;
  unsigned short* Ab = (unsigned short*)ws;
  unsigned short* WThi = Ab + NA;
  unsigned short* WTlo = WThi + NW;
  float* kvq = (float*)(WTlo + NW);
  float* kf = kvq;
  float* vf = kvq + (size_t)TOK * EMB;
  float* qf = kvq + (size_t)2 * TOK * EMB;
  float* out = (float*)d_out;

  cvt_inputs<<<(3 * TOK * EMB / 4 + 255) / 256, 256, 0, stream>>>(
      key, value, query, Ab);
  cvt_wT<<<dim3(EMB / 32, EMB / 32, 3), dim3(32, 8), 0, stream>>>(
      Wk, Wv, Wq, WThi, WTlo);
  proj_gemm<<<dim3(EMB / 128, TOK / 64, 3), 256, 0, stream>>>(
      Ab, WThi, WTlo, kvq);
  attn<<<TOK / 4, 512, 0, stream>>>(kf, vf, qf, out);
}

// Round 4
// 93.821 us; speedup vs baseline: 2.6953x; 1.2355x over previous
//
#include <hip/hip_runtime.h>
#include <cstdint>

#define TOK 2048
#define EMB 768
#define WIN 64
#define QB 32          // queries per attn block
#define TCN (TOK / 16) // 128 token tiles (16-row)
#define DCN (EMB / 32) // 24 d-chunks (32-col)

typedef __attribute__((ext_vector_type(8))) __bf16 bf16x8;
typedef __attribute__((ext_vector_type(4))) float f32x4;

static __device__ __forceinline__ unsigned short f2bf(float f) {
  uint32_t x = __float_as_uint(f);
  uint32_t r = (x + 0x7fffu + ((x >> 16) & 1u)) >> 16;  // RNE
  return (unsigned short)r;
}
static __device__ __forceinline__ float bf2f(unsigned short u) {
  return __uint_as_float(((uint32_t)u) << 16);
}

static __device__ __forceinline__ void gload_lds16(const void* g, void* l) {
  __builtin_amdgcn_global_load_lds(
      (const __attribute__((address_space(1))) uint32_t*)g,
      (__attribute__((address_space(3))) uint32_t*)l, 16, 0, 0);
}

// ---------------- prep: inputs -> bf16 ----------------
__global__ __launch_bounds__(256) void cvt_inputs(
    const float* __restrict__ a0, const float* __restrict__ a1,
    const float* __restrict__ a2, unsigned short* __restrict__ hi) {
  const int64_t NE4 = (int64_t)TOK * EMB / 4;
  int64_t i = (int64_t)blockIdx.x * blockDim.x + threadIdx.x;
  if (i >= 3 * NE4) return;
  int which = (int)(i / NE4);
  int64_t loc = i - (int64_t)which * NE4;
  const float4* src = (const float4*)(which == 0 ? a0 : which == 1 ? a1 : a2);
  float4 x = src[loc];
  ushort4 h;
  h.x = f2bf(x.x); h.y = f2bf(x.y); h.z = f2bf(x.z); h.w = f2bf(x.w);
  ((ushort4*)hi)[i] = h;
}

// ---------------- prep: weights -> transposed bf16 hi/lo ----------------
__global__ void cvt_wT(const float* __restrict__ w0, const float* __restrict__ w1,
                       const float* __restrict__ w2,
                       unsigned short* __restrict__ hiT,
                       unsigned short* __restrict__ loT) {
  __shared__ float t[32][33];
  const int z = blockIdx.z;
  const float* w = (z == 0) ? w0 : (z == 1) ? w1 : w2;
  const int d0 = blockIdx.x * 32, e0 = blockIdx.y * 32;
  const int tx = threadIdx.x, ty = threadIdx.y;  // (32,8)
#pragma unroll
  for (int r = 0; r < 4; ++r)
    t[ty + r * 8][tx] = w[(size_t)(e0 + ty + r * 8) * EMB + d0 + tx];
  __syncthreads();
#pragma unroll
  for (int r = 0; r < 4; ++r) {
    const int dl = ty + r * 8, el = tx;
    const float f = t[el][dl];  // = W[e0+el][d0+dl]
    const size_t o = (size_t)z * EMB * EMB + (size_t)(d0 + dl) * EMB + e0 + el;
    unsigned short h = f2bf(f);
    hiT[o] = h;
    loT[o] = f2bf(f - bf2f(h));
  }
}

// ---------------- projections: 2-term split-bf16 MFMA GEMM ----------------
// C = Abf@(Bhi+Blo). Epilogue writes MFMA-native layouts:
//   z=0 (k), z=2 (q): hi/lo bf16 tiled [tok/16][d/32][16][32]
//   z=1 (v): bf16 V^T panels [tok/32][768][32]
__global__ __launch_bounds__(256) void proj_gemm(
    const unsigned short* __restrict__ Ab, const unsigned short* __restrict__ WThi,
    const unsigned short* __restrict__ WTlo,
    unsigned short* __restrict__ kh_t, unsigned short* __restrict__ kl_t,
    unsigned short* __restrict__ vT_p,
    unsigned short* __restrict__ qh_t, unsigned short* __restrict__ ql_t) {
  const int z = blockIdx.z;
  const int bn0 = blockIdx.x * 128;  // output col (D)
  const int bm0 = blockIdx.y * 64;   // output row (token)
  const int tid = threadIdx.x, lane = tid & 63, w = tid >> 6;
  const int wr = w >> 1, wc = w & 1;

  __shared__ unsigned short lA[64 * 32];    // 4KB
  __shared__ unsigned short lB[128 * 32];   // 8KB

  const unsigned short* Ah = Ab + (size_t)z * TOK * EMB;
  const unsigned short* Bh = WThi + (size_t)z * EMB * EMB;
  const unsigned short* Bl = WTlo + (size_t)z * EMB * EMB;

  f32x4 acc[2][4] = {};

  const int sr = lane >> 2;       // row within 16-row chunk
  const int sk = (lane & 3) * 8;  // k element offset (16B)

  for (int ph = 0; ph < 2; ++ph) {
    const unsigned short* Bsrc = (ph == 1) ? Bl : Bh;
    for (int kk = 0; kk < EMB; kk += 32) {
      __syncthreads();
#pragma unroll
      for (int c = 0; c < 3; ++c) {
        const int chunk = w + c * 4;  // 0..11: 0-3 A(64 rows), 4-11 B(128 rows)
        if (chunk < 4) {
          gload_lds16(Ah + (size_t)(bm0 + chunk * 16 + sr) * EMB + kk + sk,
                      (char*)lA + chunk * 1024);
        } else {
          const int bc = chunk - 4;
          gload_lds16(Bsrc + (size_t)(bn0 + bc * 16 + sr) * EMB + kk + sk,
                      (char*)lB + bc * 1024);
        }
      }
      __syncthreads();

      bf16x8 af[2], bfr[4];
#pragma unroll
      for (int m = 0; m < 2; ++m)
        af[m] = *(const bf16x8*)&lA[(wr * 32 + m * 16 + (lane & 15)) * 32 +
                                    (lane >> 4) * 8];
#pragma unroll
      for (int n = 0; n < 4; ++n)
        bfr[n] = *(const bf16x8*)&lB[(wc * 64 + n * 16 + (lane & 15)) * 32 +
                                     (lane >> 4) * 8];
#pragma unroll
      for (int m = 0; m < 2; ++m)
#pragma unroll
        for (int n = 0; n < 4; ++n)
          acc[m][n] = __builtin_amdgcn_mfma_f32_16x16x32_bf16(af[m], bfr[n],
                                                              acc[m][n], 0, 0, 0);
    }
  }

  // ---- epilogue: write MFMA-native layouts ----
  const int l15 = lane & 15, l4 = lane >> 4;
  if (z == 1) {
    // v -> V^T panels [tok/32][768][32]; r=0..3 contiguous -> ushort4
#pragma unroll
    for (int m = 0; m < 2; ++m) {
      const int tok0 = bm0 + wr * 32 + m * 16 + l4 * 4;
#pragma unroll
      for (int n = 0; n < 4; ++n) {
        const int d = bn0 + wc * 64 + n * 16 + l15;
        ushort4 pk;
        pk.x = f2bf(acc[m][n][0]); pk.y = f2bf(acc[m][n][1]);
        pk.z = f2bf(acc[m][n][2]); pk.w = f2bf(acc[m][n][3]);
        *(ushort4*)&vT_p[(((size_t)(tok0 >> 5) * EMB + d) << 5) + (tok0 & 31)] = pk;
      }
    }
  } else {
    unsigned short* __restrict__ dh = (z == 0) ? kh_t : qh_t;
    unsigned short* __restrict__ dl = (z == 0) ? kl_t : ql_t;
#pragma unroll
    for (int m = 0; m < 2; ++m) {
      const int tok0 = bm0 + wr * 32 + m * 16 + l4 * 4;
#pragma unroll
      for (int n = 0; n < 4; ++n) {
        const int d = bn0 + wc * 64 + n * 16 + l15;
        const size_t base =
            (((size_t)(tok0 >> 4) * DCN + (d >> 5)) * 16) * 32 + (d & 31);
#pragma unroll
        for (int r = 0; r < 4; ++r) {
          const float f = acc[m][n][r];
          const unsigned short h = f2bf(f);
          const size_t a = base + (size_t)((tok0 & 15) + r) * 32;
          dh[a] = h;
          dl[a] = f2bf(f - bf2f(h));
        }
      }
    }
  }
}

// ---------------- sliding-window attention v4: MFMA ----------------
// 64 blocks x 8 waves. QB=32 queries, 192 key slots (12 N-tiles).
// QK^T: 3-term split bf16, A/B frags DIRECT from global tiled layouts
// (wave-contiguous 1KB dwordx4 loads, no LDS). Softmax in C-layout regs
// (4-step shfl within 16-lane groups + LDS cross-wave combine); 1/(sum*L)
// folded into P. P -> LDS (bf16) -> A-frags for PV; V^T panel B-frags
// direct from global. Out fp32.
__global__ __launch_bounds__(512) void attn_mfma(
    const unsigned short* __restrict__ kh_t, const unsigned short* __restrict__ kl_t,
    const unsigned short* __restrict__ qh_t, const unsigned short* __restrict__ ql_t,
    const unsigned short* __restrict__ vT_p, float* __restrict__ out) {
  const int bid = ((int)blockIdx.x & 7) * 8 + ((int)blockIdx.x >> 3);  // XCD swz
  const int t0 = bid * QB;
  const int js0 = t0 - 64;  // first key slot token (may be <0)
  const int tid = threadIdx.x, lane = tid & 63, w = tid >> 6;
  const int mg = w >> 2, nw = w & 3;  // M-group (16q), N-wave (48 keys)
  const int l15 = lane & 15, l4 = lane >> 4;

  __shared__ unsigned short P_lds[QB][208];  // 13.3KB, 16B-aligned rows
  __shared__ float smax[2][16][4];
  __shared__ float ssum[2][16][4];

  // ---- QK^T ----
  f32x4 s[3] = {};
  const int foff = l15 * 32 + l4 * 8;  // frag offset within [16][32] tile
  const size_t a_base = ((size_t)((t0 >> 4) + mg) * DCN) * 512 + foff;
  size_t b_base[3];
#pragma unroll
  for (int n = 0; n < 3; ++n) {
    const int jn = js0 + (nw * 3 + n) * 16;
    const int tc = min(max(jn >> 4, 0), TCN - 1);  // clamp; masked later
    b_base[n] = ((size_t)tc * DCN) * 512 + foff;
  }
#pragma unroll 2
  for (int kk = 0; kk < DCN; ++kk) {
    const bf16x8 ah = *(const bf16x8*)&qh_t[a_base + (size_t)kk * 512];
    const bf16x8 al = *(const bf16x8*)&ql_t[a_base + (size_t)kk * 512];
#pragma unroll
    for (int n = 0; n < 3; ++n) {
      const bf16x8 bh = *(const bf16x8*)&kh_t[b_base[n] + (size_t)kk * 512];
      const bf16x8 bl = *(const bf16x8*)&kl_t[b_base[n] + (size_t)kk * 512];
      s[n] = __builtin_amdgcn_mfma_f32_16x16x32_bf16(ah, bh, s[n], 0, 0, 0);
      s[n] = __builtin_amdgcn_mfma_f32_16x16x32_bf16(al, bh, s[n], 0, 0, 0);
      s[n] = __builtin_amdgcn_mfma_f32_16x16x32_bf16(ah, bl, s[n], 0, 0, 0);
    }
  }

  // ---- mask + scale (C-layout: col=key=l15, row=query=l4*4+r) ----
  const float SC = 0.03608439182435161f;  // 768^-0.5
  const int qrow0 = t0 + mg * 16 + l4 * 4;
  float sv[3][4];
#pragma unroll
  for (int n = 0; n < 3; ++n) {
    const int j = js0 + (nw * 3 + n) * 16 + l15;
#pragma unroll
    for (int r = 0; r < 4; ++r) {
      const int t = qrow0 + r;
      const bool ok = (j >= 0) && (j < TOK) && (j >= t - WIN) && (j <= t + WIN);
      sv[n][r] = ok ? s[n][r] * SC : -1e30f;
    }
  }

  // ---- softmax: local reduce (16-lane groups) + cross-wave combine ----
  float mx[4];
#pragma unroll
  for (int r = 0; r < 4; ++r) {
    mx[r] = fmaxf(sv[0][r], fmaxf(sv[1][r], sv[2][r]));
#pragma unroll
    for (int off = 1; off < 16; off <<= 1)
      mx[r] = fmaxf(mx[r], __shfl_xor(mx[r], off));
  }
  if (l15 == 0) {
#pragma unroll
    for (int r = 0; r < 4; ++r) smax[mg][l4 * 4 + r][nw] = mx[r];
  }
  __syncthreads();
  float gm[4];
#pragma unroll
  for (int r = 0; r < 4; ++r) {
    const float4 m4 = *(const float4*)smax[mg][l4 * 4 + r];
    gm[r] = fmaxf(fmaxf(m4.x, m4.y), fmaxf(m4.z, m4.w));
  }
  float ps[3][4], sum[4] = {0.f, 0.f, 0.f, 0.f};
#pragma unroll
  for (int n = 0; n < 3; ++n)
#pragma unroll
    for (int r = 0; r < 4; ++r) {
      const float e = __expf(sv[n][r] - gm[r]);
      ps[n][r] = e;
      sum[r] += e;
    }
#pragma unroll
  for (int r = 0; r < 4; ++r) {
#pragma unroll
    for (int off = 1; off < 16; off <<= 1) sum[r] += __shfl_xor(sum[r], off);
  }
  if (l15 == 0) {
#pragma unroll
    for (int r = 0; r < 4; ++r) ssum[mg][l4 * 4 + r][nw] = sum[r];
  }
  __syncthreads();
  float rcp[4];
#pragma unroll
  for (int r = 0; r < 4; ++r) {
    const float4 s4 = *(const float4*)ssum[mg][l4 * 4 + r];
    const int t = qrow0 + r;
    const int len = min(TOK, t + WIN + 1) - max(0, t - WIN);
    rcp[r] = 1.0f / ((s4.x + s4.y + s4.z + s4.w) * (float)len);
  }
  // P (with 1/(sum*L) folded) -> LDS bf16
#pragma unroll
  for (int n = 0; n < 3; ++n)
#pragma unroll
    for (int r = 0; r < 4; ++r)
      P_lds[mg * 16 + l4 * 4 + r][(nw * 3 + n) * 16 + l15] =
          f2bf(ps[n][r] * rcp[r]);
  __syncthreads();

  // ---- PV: wave = (mg, 12 d-tiles); 6 K-steps of 32 keys ----
  f32x4 o[12] = {};
  const int dbase = nw * 192;
  const int cb = bid - 2;  // js0 >> 5
#pragma unroll 2
  for (int kc = 0; kc < 6; ++kc) {
    const int c = min(max(cb + kc, 0), TOK / 32 - 1);  // clamp; P=0 masks
    const bf16x8 pa = *(const bf16x8*)&P_lds[mg * 16 + l15][kc * 32 + l4 * 8];
    const size_t vb = (size_t)c * (EMB * 32);
#pragma unroll
    for (int n = 0; n < 12; ++n) {
      const int d = dbase + n * 16 + l15;
      const bf16x8 vbf = *(const bf16x8*)&vT_p[vb + (size_t)d * 32 + l4 * 8];
      o[n] = __builtin_amdgcn_mfma_f32_16x16x32_bf16(pa, vbf, o[n], 0, 0, 0);
    }
  }

  // ---- epilogue ----
#pragma unroll
  for (int n = 0; n < 12; ++n) {
    const int d = dbase + n * 16 + l15;
#pragma unroll
    for (int r = 0; r < 4; ++r)
      out[(size_t)(qrow0 + r) * EMB + d] = o[n][r];
  }
}

extern "C" void kernel_launch(void* const* d_in, const int* in_sizes, int n_in,
                              void* d_out, int out_size, void* d_ws, size_t ws_size,
                              hipStream_t stream) {
  const float* key = (const float*)d_in[0];
  const float* value = (const float*)d_in[1];
  const float* query = (const float*)d_in[2];
  const float* Wk = (const float*)d_in[3];
  const float* Wv = (const float*)d_in[4];
  const float* Wq = (const float*)d_in[5];

  // ws layout (~32.3 MB):
  // Ab[3*2048*768] | WThi[3*768*768] | WTlo | kh_t | kl_t | qh_t | ql_t | vT_p
  unsigned short* ws = (unsigned short*)d_ws;
  const size_t NA = (size_t)3 * TOK * EMB;
  const size_t NW = (size_t)3 * EMB * EMB;
  const size_t NM = (size_t)TOK * EMB;
  unsigned short* Ab = ws;
  unsigned short* WThi = Ab + NA;
  unsigned short* WTlo = WThi + NW;
  unsigned short* kh_t = WTlo + NW;
  unsigned short* kl_t = kh_t + NM;
  unsigned short* qh_t = kl_t + NM;
  unsigned short* ql_t = qh_t + NM;
  unsigned short* vT_p = ql_t + NM;
  float* out = (float*)d_out;

  cvt_inputs<<<(3 * TOK * EMB / 4 + 255) / 256, 256, 0, stream>>>(
      key, value, query, Ab);
  cvt_wT<<<dim3(EMB / 32, EMB / 32, 3), dim3(32, 8), 0, stream>>>(
      Wk, Wv, Wq, WThi, WTlo);
  proj_gemm<<<dim3(EMB / 128, TOK / 64, 3), 256, 0, stream>>>(
      Ab, WThi, WTlo, kh_t, kl_t, vT_p, qh_t, ql_t);
  attn_mfma<<<64, 512, 0, stream>>>(kh_t, kl_t, qh_t, ql_t, vT_p, out);
}

// Round 5
// 68.206 us; speedup vs baseline: 3.7075x; 1.3755x over previous
//
#include <hip/hip_runtime.h>
#include <cstdint>

#define TOK 2048
#define EMB 768
#define WIN 64
#define TCN (TOK / 16) // 128 token tiles (16-row)
#define DCN (EMB / 32) // 24 d-chunks (32-col)

typedef __attribute__((ext_vector_type(8))) __bf16 bf16x8;
typedef __attribute__((ext_vector_type(4))) float f32x4;

static __device__ __forceinline__ unsigned short f2bf(float f) {
  uint32_t x = __float_as_uint(f);
  uint32_t r = (x + 0x7fffu + ((x >> 16) & 1u)) >> 16;  // RNE
  return (unsigned short)r;
}
static __device__ __forceinline__ float bf2f(unsigned short u) {
  return __uint_as_float(((uint32_t)u) << 16);
}

static __device__ __forceinline__ void gload_lds16(const void* g, void* l) {
  __builtin_amdgcn_global_load_lds(
      (const __attribute__((address_space(1))) uint32_t*)g,
      (__attribute__((address_space(3))) uint32_t*)l, 16, 0, 0);
}

// ---------------- prep: inputs -> bf16 ----------------
__global__ __launch_bounds__(256) void cvt_inputs(
    const float* __restrict__ a0, const float* __restrict__ a1,
    const float* __restrict__ a2, unsigned short* __restrict__ hi) {
  const int64_t NE4 = (int64_t)TOK * EMB / 4;
  int64_t i = (int64_t)blockIdx.x * blockDim.x + threadIdx.x;
  if (i >= 3 * NE4) return;
  int which = (int)(i / NE4);
  int64_t loc = i - (int64_t)which * NE4;
  const float4* src = (const float4*)(which == 0 ? a0 : which == 1 ? a1 : a2);
  float4 x = src[loc];
  ushort4 h;
  h.x = f2bf(x.x); h.y = f2bf(x.y); h.z = f2bf(x.z); h.w = f2bf(x.w);
  ((ushort4*)hi)[i] = h;
}

// ---------------- prep: weights -> transposed bf16 hi/lo ----------------
__global__ void cvt_wT(const float* __restrict__ w0, const float* __restrict__ w1,
                       const float* __restrict__ w2,
                       unsigned short* __restrict__ hiT,
                       unsigned short* __restrict__ loT) {
  __shared__ float t[32][33];
  const int z = blockIdx.z;
  const float* w = (z == 0) ? w0 : (z == 1) ? w1 : w2;
  const int d0 = blockIdx.x * 32, e0 = blockIdx.y * 32;
  const int tx = threadIdx.x, ty = threadIdx.y;  // (32,8)
#pragma unroll
  for (int r = 0; r < 4; ++r)
    t[ty + r * 8][tx] = w[(size_t)(e0 + ty + r * 8) * EMB + d0 + tx];
  __syncthreads();
#pragma unroll
  for (int r = 0; r < 4; ++r) {
    const int dl = ty + r * 8, el = tx;
    const float f = t[el][dl];  // = W[e0+el][d0+dl]
    const size_t o = (size_t)z * EMB * EMB + (size_t)(d0 + dl) * EMB + e0 + el;
    unsigned short h = f2bf(f);
    hiT[o] = h;
    loT[o] = f2bf(f - bf2f(h));
  }
}

// ---------------- projections: 2-term split-bf16 MFMA GEMM ----------------
// C = Abf@(Bhi+Blo). Epilogue writes MFMA-native layouts:
//   z=0 (k), z=2 (q): hi/lo bf16 tiled [tok/16][d/32][16][32]
//   z=1 (v): bf16 V^T panels [tok/32][768][32]
__global__ __launch_bounds__(256) void proj_gemm(
    const unsigned short* __restrict__ Ab, const unsigned short* __restrict__ WThi,
    const unsigned short* __restrict__ WTlo,
    unsigned short* __restrict__ kh_t, unsigned short* __restrict__ kl_t,
    unsigned short* __restrict__ vT_p,
    unsigned short* __restrict__ qh_t, unsigned short* __restrict__ ql_t) {
  const int z = blockIdx.z;
  const int bn0 = blockIdx.x * 128;  // output col (D)
  const int bm0 = blockIdx.y * 64;   // output row (token)
  const int tid = threadIdx.x, lane = tid & 63, w = tid >> 6;
  const int wr = w >> 1, wc = w & 1;

  __shared__ unsigned short lA[64 * 32];    // 4KB
  __shared__ unsigned short lB[128 * 32];   // 8KB

  const unsigned short* Ah = Ab + (size_t)z * TOK * EMB;
  const unsigned short* Bh = WThi + (size_t)z * EMB * EMB;
  const unsigned short* Bl = WTlo + (size_t)z * EMB * EMB;

  f32x4 acc[2][4] = {};

  const int sr = lane >> 2;       // row within 16-row chunk
  const int sk = (lane & 3) * 8;  // k element offset (16B)

  for (int ph = 0; ph < 2; ++ph) {
    const unsigned short* Bsrc = (ph == 1) ? Bl : Bh;
    for (int kk = 0; kk < EMB; kk += 32) {
      __syncthreads();
#pragma unroll
      for (int c = 0; c < 3; ++c) {
        const int chunk = w + c * 4;  // 0..11: 0-3 A(64 rows), 4-11 B(128 rows)
        if (chunk < 4) {
          gload_lds16(Ah + (size_t)(bm0 + chunk * 16 + sr) * EMB + kk + sk,
                      (char*)lA + chunk * 1024);
        } else {
          const int bc = chunk - 4;
          gload_lds16(Bsrc + (size_t)(bn0 + bc * 16 + sr) * EMB + kk + sk,
                      (char*)lB + bc * 1024);
        }
      }
      __syncthreads();

      bf16x8 af[2], bfr[4];
#pragma unroll
      for (int m = 0; m < 2; ++m)
        af[m] = *(const bf16x8*)&lA[(wr * 32 + m * 16 + (lane & 15)) * 32 +
                                    (lane >> 4) * 8];
#pragma unroll
      for (int n = 0; n < 4; ++n)
        bfr[n] = *(const bf16x8*)&lB[(wc * 64 + n * 16 + (lane & 15)) * 32 +
                                     (lane >> 4) * 8];
#pragma unroll
      for (int m = 0; m < 2; ++m)
#pragma unroll
        for (int n = 0; n < 4; ++n)
          acc[m][n] = __builtin_amdgcn_mfma_f32_16x16x32_bf16(af[m], bfr[n],
                                                              acc[m][n], 0, 0, 0);
    }
  }

  // ---- epilogue: write MFMA-native layouts ----
  const int l15 = lane & 15, l4 = lane >> 4;
  if (z == 1) {
#pragma unroll
    for (int m = 0; m < 2; ++m) {
      const int tok0 = bm0 + wr * 32 + m * 16 + l4 * 4;
#pragma unroll
      for (int n = 0; n < 4; ++n) {
        const int d = bn0 + wc * 64 + n * 16 + l15;
        ushort4 pk;
        pk.x = f2bf(acc[m][n][0]); pk.y = f2bf(acc[m][n][1]);
        pk.z = f2bf(acc[m][n][2]); pk.w = f2bf(acc[m][n][3]);
        *(ushort4*)&vT_p[(((size_t)(tok0 >> 5) * EMB + d) << 5) + (tok0 & 31)] = pk;
      }
    }
  } else {
    unsigned short* __restrict__ dh = (z == 0) ? kh_t : qh_t;
    unsigned short* __restrict__ dl = (z == 0) ? kl_t : ql_t;
#pragma unroll
    for (int m = 0; m < 2; ++m) {
      const int tok0 = bm0 + wr * 32 + m * 16 + l4 * 4;
#pragma unroll
      for (int n = 0; n < 4; ++n) {
        const int d = bn0 + wc * 64 + n * 16 + l15;
        const size_t base =
            (((size_t)(tok0 >> 4) * DCN + (d >> 5)) * 16) * 32 + (d & 31);
#pragma unroll
        for (int r = 0; r < 4; ++r) {
          const float f = acc[m][n][r];
          const unsigned short h = f2bf(f);
          const size_t a = base + (size_t)((tok0 & 15) + r) * 32;
          dh[a] = h;
          dl[a] = f2bf(f - bf2f(h));
        }
      }
    }
  }
}

// ---------------- attn stage 1: scores -> exp -> P tiles + partial sums ----
// grid 512 = (qt 0..127) x (ksplit 0..3); 3 waves, wave owns N-tile
// nt = ks*3+w of 12. No max-subtraction (scores ~N(0,1), exp safe in fp32).
// P written in A-tile layout [qt*6+c][16 q][32 slot] bf16 (normalization
// deferred to PV). Partial row sums -> Ssum[qt][nt][16].
__global__ __launch_bounds__(192) void attn_S(
    const unsigned short* __restrict__ kh_t, const unsigned short* __restrict__ kl_t,
    const unsigned short* __restrict__ qh_t, const unsigned short* __restrict__ ql_t,
    unsigned short* __restrict__ Pg, float* __restrict__ Ssum) {
  const int bid = ((int)blockIdx.x & 7) * 64 + ((int)blockIdx.x >> 3);  // XCD swz
  const int qt = bid >> 2, ks = bid & 3;
  const int lane = threadIdx.x & 63, w = threadIdx.x >> 6;  // 0..2
  const int nt = ks * 3 + w;                                // 0..11
  const int l15 = lane & 15, l4 = lane >> 4;
  const int t0 = qt * 16;
  const int js0 = (t0 - 64) & ~31;  // 32-aligned slot base (maybe <0)
  const int foff = l15 * 32 + l4 * 8;

  const size_t a_base = (size_t)qt * DCN * 512 + foff;
  const int ttile = min(max((js0 >> 4) + nt, 0), TCN - 1);  // clamp; masked
  const size_t b_base = (size_t)ttile * DCN * 512 + foff;

  // 3 independent accumulator chains for MFMA ILP
  f32x4 shh = {}, slh = {}, shl = {};
#pragma unroll 4
  for (int kk = 0; kk < DCN; ++kk) {
    const bf16x8 ah = *(const bf16x8*)&qh_t[a_base + (size_t)kk * 512];
    const bf16x8 al = *(const bf16x8*)&ql_t[a_base + (size_t)kk * 512];
    const bf16x8 bh = *(const bf16x8*)&kh_t[b_base + (size_t)kk * 512];
    const bf16x8 bl = *(const bf16x8*)&kl_t[b_base + (size_t)kk * 512];
    shh = __builtin_amdgcn_mfma_f32_16x16x32_bf16(ah, bh, shh, 0, 0, 0);
    slh = __builtin_amdgcn_mfma_f32_16x16x32_bf16(al, bh, slh, 0, 0, 0);
    shl = __builtin_amdgcn_mfma_f32_16x16x32_bf16(ah, bl, shl, 0, 0, 0);
  }

  const float SC = 0.03608439182435161f;  // 768^-0.5
  const int j = js0 + nt * 16 + l15;      // key token for this lane's column
  const int qrow0 = t0 + l4 * 4;
  const int c = nt >> 1, colb = (nt & 1) * 16 + l15;

  float e[4];
#pragma unroll
  for (int r = 0; r < 4; ++r) {
    const int t = qrow0 + r;
    const float x = (shh[r] + slh[r] + shl[r]) * SC;
    const bool ok = (j >= 0) && (j < TOK) && (j >= t - WIN) && (j <= t + WIN);
    e[r] = ok ? __expf(x) : 0.0f;
  }
  // per-row partial sums over this tile's 16 keys (reduce within l15 group)
#pragma unroll
  for (int r = 0; r < 4; ++r) {
    float s = e[r];
#pragma unroll
    for (int off = 1; off < 16; off <<= 1) s += __shfl_xor(s, off);
    if (l15 == 0) Ssum[qt * 192 + nt * 16 + l4 * 4 + r] = s;
  }
  // P -> A-tile layout
#pragma unroll
  for (int r = 0; r < 4; ++r)
    Pg[(((size_t)qt * 6 + c) * 16 + (l4 * 4 + r)) * 32 + colb] = f2bf(e[r]);
}

// ---------------- attn stage 2: PV + normalize ----------------
// grid 512 = (qt 0..127) x (dsplit 0..3); 3 waves, wave owns 64 d-cols.
// out[q][d] = (sum_k P[q][k] V[k][d]) / (rowsum * L).
__global__ __launch_bounds__(192) void attn_PV(
    const unsigned short* __restrict__ Pg, const float* __restrict__ Ssum,
    const unsigned short* __restrict__ vT_p, float* __restrict__ out) {
  const int bid = ((int)blockIdx.x & 7) * 64 + ((int)blockIdx.x >> 3);  // XCD swz
  const int qt = bid >> 2, ds = bid & 3;
  const int tid = threadIdx.x;
  const int lane = tid & 63, w = tid >> 6;
  const int l15 = lane & 15, l4 = lane >> 4;
  const int t0 = qt * 16;
  const int js0 = (t0 - 64) & ~31;

  __shared__ float ssum_l[192];
  __shared__ float rcp_l[16];

  ssum_l[tid] = Ssum[qt * 192 + tid];
  __syncthreads();
  if (tid < 16) {
    float s = 0.f;
#pragma unroll
    for (int i = 0; i < 12; ++i) s += ssum_l[i * 16 + tid];
    const int t = t0 + tid;
    const int len = min(TOK, t + WIN + 1) - max(0, t - WIN);
    rcp_l[tid] = 1.0f / (s * (float)len);
  }

  f32x4 o[4] = {};
  const int c0 = js0 >> 5;
#pragma unroll
  for (int kc = 0; kc < 6; ++kc) {
    const bf16x8 pa =
        *(const bf16x8*)&Pg[(((size_t)qt * 6 + kc) * 16 + l15) * 32 + l4 * 8];
    const int cc = min(max(c0 + kc, 0), TOK / 32 - 1);  // clamp; P=0 masks
    const size_t vb = (size_t)cc * (EMB * 32);
#pragma unroll
    for (int n = 0; n < 4; ++n) {
      const int d = ds * 192 + w * 64 + n * 16 + l15;
      const bf16x8 vbf = *(const bf16x8*)&vT_p[vb + (size_t)d * 32 + l4 * 8];
      o[n] = __builtin_amdgcn_mfma_f32_16x16x32_bf16(pa, vbf, o[n], 0, 0, 0);
    }
  }
  __syncthreads();  // rcp_l ready

  const int qrow0 = t0 + l4 * 4;
  float rr[4];
#pragma unroll
  for (int r = 0; r < 4; ++r) rr[r] = rcp_l[l4 * 4 + r];
#pragma unroll
  for (int n = 0; n < 4; ++n) {
    const int d = ds * 192 + w * 64 + n * 16 + l15;
#pragma unroll
    for (int r = 0; r < 4; ++r)
      out[(size_t)(qrow0 + r) * EMB + d] = o[n][r] * rr[r];
  }
}

extern "C" void kernel_launch(void* const* d_in, const int* in_sizes, int n_in,
                              void* d_out, int out_size, void* d_ws, size_t ws_size,
                              hipStream_t stream) {
  const float* key = (const float*)d_in[0];
  const float* value = (const float*)d_in[1];
  const float* query = (const float*)d_in[2];
  const float* Wk = (const float*)d_in[3];
  const float* Wv = (const float*)d_in[4];
  const float* Wq = (const float*)d_in[5];

  // ws layout (~33 MB):
  // Ab | WThi | WTlo | kh_t | kl_t | qh_t | ql_t | vT_p | Pg | Ssum
  unsigned short* ws = (unsigned short*)d_ws;
  const size_t NA = (size_t)3 * TOK * EMB;
  const size_t NW = (size_t)3 * EMB * EMB;
  const size_t NM = (size_t)TOK * EMB;
  unsigned short* Ab = ws;
  unsigned short* WThi = Ab + NA;
  unsigned short* WTlo = WThi + NW;
  unsigned short* kh_t = WTlo + NW;
  unsigned short* kl_t = kh_t + NM;
  unsigned short* qh_t = kl_t + NM;
  unsigned short* ql_t = qh_t + NM;
  unsigned short* vT_p = ql_t + NM;
  unsigned short* Pg = vT_p + NM;                  // 128*6*16*32 = 393216
  float* Ssum = (float*)(Pg + (size_t)128 * 6 * 16 * 32);  // 24576 f32
  float* out = (float*)d_out;

  cvt_inputs<<<(3 * TOK * EMB / 4 + 255) / 256, 256, 0, stream>>>(
      key, value, query, Ab);
  cvt_wT<<<dim3(EMB / 32, EMB / 32, 3), dim3(32, 8), 0, stream>>>(
      Wk, Wv, Wq, WThi, WTlo);
  proj_gemm<<<dim3(EMB / 128, TOK / 64, 3), 256, 0, stream>>>(
      Ab, WThi, WTlo, kh_t, kl_t, vT_p, qh_t, ql_t);
  attn_S<<<512, 192, 0, stream>>>(kh_t, kl_t, qh_t, ql_t, Pg, Ssum);
  attn_PV<<<512, 192, 0, stream>>>(Pg, Ssum, vT_p, out);
}

// Round 6
// 46.357 us; speedup vs baseline: 5.4550x; 1.4713x over previous
//
#include <hip/hip_runtime.h>
#include <cstdint>

#define TOK 2048
#define EMB 768
#define WIN 64
#define TCN (TOK / 16) // 128 token tiles (16-row)
#define DCN (EMB / 32) // 24 d-chunks (32-col)

typedef __attribute__((ext_vector_type(8))) __bf16 bf16x8;
typedef __attribute__((ext_vector_type(4))) float f32x4;

static __device__ __forceinline__ unsigned short f2bf(float f) {
  uint32_t x = __float_as_uint(f);
  uint32_t r = (x + 0x7fffu + ((x >> 16) & 1u)) >> 16;  // RNE
  return (unsigned short)r;
}
static __device__ __forceinline__ float bf2f(unsigned short u) {
  return __uint_as_float(((uint32_t)u) << 16);
}

static __device__ __forceinline__ void gload_lds16(const void* g, void* l) {
  __builtin_amdgcn_global_load_lds(
      (const __attribute__((address_space(1))) uint32_t*)g,
      (__attribute__((address_space(3))) uint32_t*)l, 16, 0, 0);
}

// ---------------- prep: inputs -> bf16 ----------------
__global__ __launch_bounds__(256) void cvt_inputs(
    const float* __restrict__ a0, const float* __restrict__ a1,
    const float* __restrict__ a2, unsigned short* __restrict__ hi) {
  const int64_t NE4 = (int64_t)TOK * EMB / 4;
  int64_t i = (int64_t)blockIdx.x * blockDim.x + threadIdx.x;
  if (i >= 3 * NE4) return;
  int which = (int)(i / NE4);
  int64_t loc = i - (int64_t)which * NE4;
  const float4* src = (const float4*)(which == 0 ? a0 : which == 1 ? a1 : a2);
  float4 x = src[loc];
  ushort4 h;
  h.x = f2bf(x.x); h.y = f2bf(x.y); h.z = f2bf(x.z); h.w = f2bf(x.w);
  ((ushort4*)hi)[i] = h;
}

// ---------------- prep: weights -> transposed bf16 (single) ----------------
__global__ void cvt_wT(const float* __restrict__ w0, const float* __restrict__ w1,
                       const float* __restrict__ w2,
                       unsigned short* __restrict__ hiT) {
  __shared__ float t[32][33];
  const int z = blockIdx.z;
  const float* w = (z == 0) ? w0 : (z == 1) ? w1 : w2;
  const int d0 = blockIdx.x * 32, e0 = blockIdx.y * 32;
  const int tx = threadIdx.x, ty = threadIdx.y;  // (32,8)
#pragma unroll
  for (int r = 0; r < 4; ++r)
    t[ty + r * 8][tx] = w[(size_t)(e0 + ty + r * 8) * EMB + d0 + tx];
  __syncthreads();
#pragma unroll
  for (int r = 0; r < 4; ++r) {
    const int dl = ty + r * 8, el = tx;
    const float f = t[el][dl];  // = W[e0+el][d0+dl]
    hiT[(size_t)z * EMB * EMB + (size_t)(d0 + dl) * EMB + e0 + el] = f2bf(f);
  }
}

// ---------------- projections: single-term bf16 MFMA GEMM ----------------
// C = Abf@Wbf. Epilogue writes MFMA-native layouts:
//   z=0 (k), z=2 (q): bf16 tiled [tok/16][d/32][16][32]
//   z=1 (v): bf16 V^T panels [tok/32][768][32]
__global__ __launch_bounds__(256) void proj_gemm(
    const unsigned short* __restrict__ Ab, const unsigned short* __restrict__ WT,
    unsigned short* __restrict__ k_t, unsigned short* __restrict__ vT_p,
    unsigned short* __restrict__ q_t) {
  const int z = blockIdx.z;
  const int bn0 = blockIdx.x * 128;  // output col (D)
  const int bm0 = blockIdx.y * 64;   // output row (token)
  const int tid = threadIdx.x, lane = tid & 63, w = tid >> 6;
  const int wr = w >> 1, wc = w & 1;

  __shared__ unsigned short lA[64 * 32];    // 4KB
  __shared__ unsigned short lB[128 * 32];   // 8KB

  const unsigned short* Ah = Ab + (size_t)z * TOK * EMB;
  const unsigned short* Bh = WT + (size_t)z * EMB * EMB;

  f32x4 acc[2][4] = {};

  const int sr = lane >> 2;       // row within 16-row chunk
  const int sk = (lane & 3) * 8;  // k element offset (16B)

  for (int kk = 0; kk < EMB; kk += 32) {
    __syncthreads();
#pragma unroll
    for (int c = 0; c < 3; ++c) {
      const int chunk = w + c * 4;  // 0..11: 0-3 A(64 rows), 4-11 B(128 rows)
      if (chunk < 4) {
        gload_lds16(Ah + (size_t)(bm0 + chunk * 16 + sr) * EMB + kk + sk,
                    (char*)lA + chunk * 1024);
      } else {
        const int bc = chunk - 4;
        gload_lds16(Bh + (size_t)(bn0 + bc * 16 + sr) * EMB + kk + sk,
                    (char*)lB + bc * 1024);
      }
    }
    __syncthreads();

    bf16x8 af[2], bfr[4];
#pragma unroll
    for (int m = 0; m < 2; ++m)
      af[m] = *(const bf16x8*)&lA[(wr * 32 + m * 16 + (lane & 15)) * 32 +
                                  (lane >> 4) * 8];
#pragma unroll
    for (int n = 0; n < 4; ++n)
      bfr[n] = *(const bf16x8*)&lB[(wc * 64 + n * 16 + (lane & 15)) * 32 +
                                   (lane >> 4) * 8];
#pragma unroll
    for (int m = 0; m < 2; ++m)
#pragma unroll
      for (int n = 0; n < 4; ++n)
        acc[m][n] = __builtin_amdgcn_mfma_f32_16x16x32_bf16(af[m], bfr[n],
                                                            acc[m][n], 0, 0, 0);
  }

  // ---- epilogue: write MFMA-native layouts ----
  const int l15 = lane & 15, l4 = lane >> 4;
  if (z == 1) {
#pragma unroll
    for (int m = 0; m < 2; ++m) {
      const int tok0 = bm0 + wr * 32 + m * 16 + l4 * 4;
#pragma unroll
      for (int n = 0; n < 4; ++n) {
        const int d = bn0 + wc * 64 + n * 16 + l15;
        ushort4 pk;
        pk.x = f2bf(acc[m][n][0]); pk.y = f2bf(acc[m][n][1]);
        pk.z = f2bf(acc[m][n][2]); pk.w = f2bf(acc[m][n][3]);
        *(ushort4*)&vT_p[(((size_t)(tok0 >> 5) * EMB + d) << 5) + (tok0 & 31)] = pk;
      }
    }
  } else {
    unsigned short* __restrict__ dh = (z == 0) ? k_t : q_t;
#pragma unroll
    for (int m = 0; m < 2; ++m) {
      const int tok0 = bm0 + wr * 32 + m * 16 + l4 * 4;
#pragma unroll
      for (int n = 0; n < 4; ++n) {
        const int d = bn0 + wc * 64 + n * 16 + l15;
        const size_t base =
            (((size_t)(tok0 >> 4) * DCN + (d >> 5)) * 16) * 32 + (d & 31);
#pragma unroll
        for (int r = 0; r < 4; ++r)
          dh[base + (size_t)((tok0 & 15) + r) * 32] = f2bf(acc[m][n][r]);
      }
    }
  }
}

// ---------------- attn stage 1: scores -> exp -> P tiles + partial sums ----
// grid 512 = (qt 0..127) x (ksplit 0..3); 3 waves, wave owns N-tile
// nt = ks*3+w of 12. Single bf16 chain (q,k already near-fp32 from proj acc).
// No max-subtraction (scores ~N(0,1), exp safe in fp32). P -> A-tile layout
// [qt*6+c][16 q][32 slot] bf16; partial row sums -> Ssum[qt][nt][16].
__global__ __launch_bounds__(192) void attn_S(
    const unsigned short* __restrict__ k_t, const unsigned short* __restrict__ q_t,
    unsigned short* __restrict__ Pg, float* __restrict__ Ssum) {
  const int bid = ((int)blockIdx.x & 7) * 64 + ((int)blockIdx.x >> 3);  // XCD swz
  const int qt = bid >> 2, ks = bid & 3;
  const int lane = threadIdx.x & 63, w = threadIdx.x >> 6;  // 0..2
  const int nt = ks * 3 + w;                                // 0..11
  const int l15 = lane & 15, l4 = lane >> 4;
  const int t0 = qt * 16;
  const int js0 = (t0 - 64) & ~31;  // 32-aligned slot base (maybe <0)
  const int foff = l15 * 32 + l4 * 8;

  const size_t a_base = (size_t)qt * DCN * 512 + foff;
  const int ttile = min(max((js0 >> 4) + nt, 0), TCN - 1);  // clamp; masked
  const size_t b_base = (size_t)ttile * DCN * 512 + foff;

  f32x4 s = {};
#pragma unroll 8
  for (int kk = 0; kk < DCN; ++kk) {
    const bf16x8 ah = *(const bf16x8*)&q_t[a_base + (size_t)kk * 512];
    const bf16x8 bh = *(const bf16x8*)&k_t[b_base + (size_t)kk * 512];
    s = __builtin_amdgcn_mfma_f32_16x16x32_bf16(ah, bh, s, 0, 0, 0);
  }

  const float SC = 0.03608439182435161f;  // 768^-0.5
  const int j = js0 + nt * 16 + l15;      // key token for this lane's column
  const int qrow0 = t0 + l4 * 4;
  const int c = nt >> 1, colb = (nt & 1) * 16 + l15;

  float e[4];
#pragma unroll
  for (int r = 0; r < 4; ++r) {
    const int t = qrow0 + r;
    const bool ok = (j >= 0) && (j < TOK) && (j >= t - WIN) && (j <= t + WIN);
    e[r] = ok ? __expf(s[r] * SC) : 0.0f;
  }
  // per-row partial sums over this tile's 16 keys (reduce within l15 group)
#pragma unroll
  for (int r = 0; r < 4; ++r) {
    float sm = e[r];
#pragma unroll
    for (int off = 1; off < 16; off <<= 1) sm += __shfl_xor(sm, off);
    if (l15 == 0) Ssum[qt * 192 + nt * 16 + l4 * 4 + r] = sm;
  }
  // P -> A-tile layout
#pragma unroll
  for (int r = 0; r < 4; ++r)
    Pg[(((size_t)qt * 6 + c) * 16 + (l4 * 4 + r)) * 32 + colb] = f2bf(e[r]);
}

// ---------------- attn stage 2: PV + normalize ----------------
// grid 512 = (qt 0..127) x (dsplit 0..3); 3 waves, wave owns 64 d-cols.
// out[q][d] = (sum_k P[q][k] V[k][d]) / (rowsum * L).
__global__ __launch_bounds__(192) void attn_PV(
    const unsigned short* __restrict__ Pg, const float* __restrict__ Ssum,
    const unsigned short* __restrict__ vT_p, float* __restrict__ out) {
  const int bid = ((int)blockIdx.x & 7) * 64 + ((int)blockIdx.x >> 3);  // XCD swz
  const int qt = bid >> 2, ds = bid & 3;
  const int tid = threadIdx.x;
  const int lane = tid & 63, w = tid >> 6;
  const int l15 = lane & 15, l4 = lane >> 4;
  const int t0 = qt * 16;
  const int js0 = (t0 - 64) & ~31;

  __shared__ float ssum_l[192];
  __shared__ float rcp_l[16];

  ssum_l[tid] = Ssum[qt * 192 + tid];
  __syncthreads();
  if (tid < 16) {
    float s = 0.f;
#pragma unroll
    for (int i = 0; i < 12; ++i) s += ssum_l[i * 16 + tid];
    const int t = t0 + tid;
    const int len = min(TOK, t + WIN + 1) - max(0, t - WIN);
    rcp_l[tid] = 1.0f / (s * (float)len);
  }

  f32x4 o[4] = {};
  const int c0 = js0 >> 5;
#pragma unroll
  for (int kc = 0; kc < 6; ++kc) {
    const bf16x8 pa =
        *(const bf16x8*)&Pg[(((size_t)qt * 6 + kc) * 16 + l15) * 32 + l4 * 8];
    const int cc = min(max(c0 + kc, 0), TOK / 32 - 1);  // clamp; P=0 masks
    const size_t vb = (size_t)cc * (EMB * 32);
#pragma unroll
    for (int n = 0; n < 4; ++n) {
      const int d = ds * 192 + w * 64 + n * 16 + l15;
      const bf16x8 vbf = *(const bf16x8*)&vT_p[vb + (size_t)d * 32 + l4 * 8];
      o[n] = __builtin_amdgcn_mfma_f32_16x16x32_bf16(pa, vbf, o[n], 0, 0, 0);
    }
  }
  __syncthreads();  // rcp_l ready

  const int qrow0 = t0 + l4 * 4;
  float rr[4];
#pragma unroll
  for (int r = 0; r < 4; ++r) rr[r] = rcp_l[l4 * 4 + r];
#pragma unroll
  for (int n = 0; n < 4; ++n) {
    const int d = ds * 192 + w * 64 + n * 16 + l15;
#pragma unroll
    for (int r = 0; r < 4; ++r)
      out[(size_t)(qrow0 + r) * EMB + d] = o[n][r] * rr[r];
  }
}

extern "C" void kernel_launch(void* const* d_in, const int* in_sizes, int n_in,
                              void* d_out, int out_size, void* d_ws, size_t ws_size,
                              hipStream_t stream) {
  const float* key = (const float*)d_in[0];
  const float* value = (const float*)d_in[1];
  const float* query = (const float*)d_in[2];
  const float* Wk = (const float*)d_in[3];
  const float* Wv = (const float*)d_in[4];
  const float* Wq = (const float*)d_in[5];

  // ws layout (~25 MB): Ab | WT | k_t | q_t | vT_p | Pg | Ssum
  unsigned short* ws = (unsigned short*)d_ws;
  const size_t NA = (size_t)3 * TOK * EMB;
  const size_t NW = (size_t)3 * EMB * EMB;
  const size_t NM = (size_t)TOK * EMB;
  unsigned short* Ab = ws;
  unsigned short* WT = Ab + NA;
  unsigned short* k_t = WT + NW;
  unsigned short* q_t = k_t + NM;
  unsigned short* vT_p = q_t + NM;
  unsigned short* Pg = vT_p + NM;                  // 128*6*16*32 = 393216
  float* Ssum = (float*)(Pg + (size_t)128 * 6 * 16 * 32);  // 24576 f32
  float* out = (float*)d_out;

  cvt_inputs<<<(3 * TOK * EMB / 4 + 255) / 256, 256, 0, stream>>>(
      key, value, query, Ab);
  cvt_wT<<<dim3(EMB / 32, EMB / 32, 3), dim3(32, 8), 0, stream>>>(
      Wk, Wv, Wq, WT);
  proj_gemm<<<dim3(EMB / 128, TOK / 64, 3), 256, 0, stream>>>(
      Ab, WT, k_t, vT_p, q_t);
  attn_S<<<512, 192, 0, stream>>>(k_t, q_t, Pg, Ssum);
  attn_PV<<<512, 192, 0, stream>>>(Pg, Ssum, vT_p, out);
}